// Round 17
// baseline (276.911 us; speedup 1.0000x reference)
//
#include <hip/hip_runtime.h>
#include <math.h>

// B=64, S=64, H_DIM=768, N_HEADS=12, D=64. All I/O f32.
// 4 kernels. ws bytes: qkvb u16[9437184] @0 ; Zh u16[3145728] @18874368 ;
//           part f32[16][64][4096] @25165824
// d_out f32: y [262144] then masked_scores [3145728].
// Masked positions: ref=-inf -> finite NEG_BIG (never materialize inf:
// finite-math folds ==-INFINITY; expf(NEG_BIG-m)==0).
// All GEMMs plain bf16 MFMA, f32 accum.
// mfma_f32_16x16x32_bf16: A row=ln&15,k=(ln>>4)*8+j; B col=ln&15;
// C/D col=ln&15,row=(ln>>4)*4+reg.
// Z frag order: z_flat[b][k] at ((rt*1536+kf)*64+lz)*8+j, rt=b>>4, kf=k>>5,
// lz=((k>>3)&3)*16+(b&15), j=k&7 -> contiguous 1KB wave reads/stages.
// k_lin v13 = r16 schedule at HALF sub size (BK=64) so LDS=34.4KB ->
// 4 blocks/CU, 16 waves/CU (was 8). Theory under test: W-stream cap
// (~3.4TB/s, schedule-insensitive r7-r16) is per-CU outstanding-miss
// capacity scaling with resident waves (copy ubench hits 6.3 at 32
// waves/CU; r6's 0.94 = 3.5/4 line-overfetch fits). Doubling waves/CU
// should raise k_lin BW if queue-limited; flat if MSHR-structural.

#define NEG_BIG (-1.0e30f)

typedef __attribute__((ext_vector_type(8))) short bf16x8;
typedef __attribute__((ext_vector_type(4))) float f32x4;
typedef const __attribute__((address_space(1))) void gvoid_t;
typedef __attribute__((address_space(3))) void svoid_t;

static __device__ __forceinline__ unsigned short f2bf(float x) {
    unsigned u = __builtin_bit_cast(unsigned, x);
    return (unsigned short)((u + 0x7FFFu + ((u >> 16) & 1u)) >> 16);   // RNE
}
static __device__ __forceinline__ ushort4 f2bf4(float4 v) {
    ushort4 r; r.x = f2bf(v.x); r.y = f2bf(v.y); r.z = f2bf(v.z); r.w = f2bf(v.w); return r;
}

// ---------------- Kernel 1: QKV GEMM, plain bf16 MFMA ----------------
__global__ __launch_bounds__(256, 4) void k_qkv(const float* __restrict__ X,
                                                const float* __restrict__ Wp,
                                                unsigned short* __restrict__ qkvb) {
    __shared__ unsigned short Ah[128][72];
    __shared__ unsigned short Bh[128][72];
    const int t  = threadIdx.x;
    const int wv = t >> 6, ln = t & 63;
    const int lr = ln & 15;
    const int kq = (ln >> 4) * 8;
    const int rbase = (ln >> 4) * 4;
    const int m0 = (blockIdx.x / 18) * 128;
    const int j0 = (blockIdx.x % 18) * 128;
    const f32x4 zero4 = {0.f, 0.f, 0.f, 0.f};

    f32x4 acc[2][8];
#pragma unroll
    for (int rt = 0; rt < 2; ++rt)
#pragma unroll
        for (int ct = 0; ct < 8; ++ct) acc[rt][ct] = zero4;

    for (int k0 = 0; k0 < 768; k0 += 64) {
#pragma unroll
        for (int i = 0; i < 8; ++i) {
            const int q   = t + 256 * i;
            const int row = q >> 4;
            const int kc  = (q & 15) * 4;
            float4 xa = *reinterpret_cast<const float4*>(&X[(size_t)(m0 + row) * 768 + k0 + kc]);
            *reinterpret_cast<ushort4*>(&Ah[row][kc]) = f2bf4(xa);
            float4 wb = *reinterpret_cast<const float4*>(&Wp[(size_t)(j0 + row) * 768 + k0 + kc]);
            *reinterpret_cast<ushort4*>(&Bh[row][kc]) = f2bf4(wb);
        }
        __syncthreads();
#pragma unroll
        for (int ks = 0; ks < 2; ++ks) {
            const int kb = ks * 32 + kq;
            bf16x8 a0 = *reinterpret_cast<const bf16x8*>(&Ah[wv * 32 + lr][kb]);
            bf16x8 a1 = *reinterpret_cast<const bf16x8*>(&Ah[wv * 32 + 16 + lr][kb]);
#pragma unroll
            for (int ct = 0; ct < 8; ++ct) {
                bf16x8 bh = *reinterpret_cast<const bf16x8*>(&Bh[ct * 16 + lr][kb]);
                acc[0][ct] = __builtin_amdgcn_mfma_f32_16x16x32_bf16(a0, bh, acc[0][ct], 0, 0, 0);
                acc[1][ct] = __builtin_amdgcn_mfma_f32_16x16x32_bf16(a1, bh, acc[1][ct], 0, 0, 0);
            }
        }
        __syncthreads();
    }
#pragma unroll
    for (int rt = 0; rt < 2; ++rt)
#pragma unroll
        for (int ct = 0; ct < 8; ++ct)
#pragma unroll
            for (int r = 0; r < 4; ++r) {
                const int m = m0 + wv * 32 + rt * 16 + rbase + r;
                const int j = j0 + ct * 16 + lr;
                const int b = m >> 6, s = m & 63;
                const int n = j / 192, f = j % 192;
                qkvb[(((size_t)b * 12 + n) * 64 + s) * 192 + f] = f2bf(acc[rt][ct][r]);
            }
}

// ---------------- Kernel 2: attention per (b,n), plain bf16 MFMA ----------------
__global__ __launch_bounds__(256, 4) void k_attn(const unsigned short* __restrict__ qkvb,
                                                 float* __restrict__ msk,
                                                 unsigned short* __restrict__ Zh) {
    __shared__ unsigned short Qh[64][72];
    __shared__ unsigned short Kh[64][72];
    __shared__ unsigned short Vth[64][72];   // V transposed [d][s]
    __shared__ unsigned short Ph[64][72];
    const int t  = threadIdx.x;
    const int wv = t >> 6, ln = t & 63;
    const int lr = ln & 15;
    const int kq = (ln >> 4) * 8;
    const int rbase = (ln >> 4) * 4;
    const int bn = blockIdx.x;
    const int bb = bn / 12, nn = bn % 12;
    const unsigned short* base = qkvb + (size_t)bn * 12288;
    const f32x4 zero4 = {0.f, 0.f, 0.f, 0.f};

#pragma unroll
    for (int i = 0; i < 6; ++i) {
        const int q   = t + 256 * i;
        const int row = q / 24;
        const int c8  = (q % 24) * 8;
        const int sec = c8 >> 6;
        const int d0  = c8 & 63;
        bf16x8 v = *reinterpret_cast<const bf16x8*>(&base[(size_t)row * 192 + c8]);
        if (sec == 0) {
            *reinterpret_cast<bf16x8*>(&Qh[row][d0]) = v;
        } else if (sec == 1) {
            *reinterpret_cast<bf16x8*>(&Kh[row][d0]) = v;
        } else {
#pragma unroll
            for (int jj = 0; jj < 8; ++jj) Vth[d0 + jj][row] = (unsigned short)v[jj];
        }
    }
    __syncthreads();

    f32x4 acc[4];
#pragma unroll
    for (int ct = 0; ct < 4; ++ct) acc[ct] = zero4;
#pragma unroll
    for (int ks = 0; ks < 2; ++ks) {
        const int kb = ks * 32 + kq;
        bf16x8 qh = *reinterpret_cast<const bf16x8*>(&Qh[wv * 16 + lr][kb]);
#pragma unroll
        for (int ct = 0; ct < 4; ++ct) {
            bf16x8 kh = *reinterpret_cast<const bf16x8*>(&Kh[ct * 16 + lr][kb]);
            acc[ct] = __builtin_amdgcn_mfma_f32_16x16x32_bf16(qh, kh, acc[ct], 0, 0, 0);
        }
    }

    float s_[4][4];
#pragma unroll
    for (int ct = 0; ct < 4; ++ct)
#pragma unroll
        for (int r = 0; r < 4; ++r) {
            const int row = wv * 16 + rbase + r;
            const int col = ct * 16 + lr;
            float s = (col > row) ? NEG_BIG : acc[ct][r] * 0.125f;
            s_[ct][r] = s;
            msk[(size_t)bn * 4096 + (size_t)row * 64 + col] = s;
        }
    float m[4], sum[4], p[4][4];
#pragma unroll
    for (int r = 0; r < 4; ++r)
        m[r] = fmaxf(fmaxf(s_[0][r], s_[1][r]), fmaxf(s_[2][r], s_[3][r]));
#pragma unroll
    for (int off = 1; off <= 8; off <<= 1)
#pragma unroll
        for (int r = 0; r < 4; ++r) m[r] = fmaxf(m[r], __shfl_xor(m[r], off));
#pragma unroll
    for (int r = 0; r < 4; ++r) sum[r] = 0.f;
#pragma unroll
    for (int ct = 0; ct < 4; ++ct)
#pragma unroll
        for (int r = 0; r < 4; ++r) { p[ct][r] = expf(s_[ct][r] - m[r]); sum[r] += p[ct][r]; }
#pragma unroll
    for (int off = 1; off <= 8; off <<= 1)
#pragma unroll
        for (int r = 0; r < 4; ++r) sum[r] += __shfl_xor(sum[r], off);
#pragma unroll
    for (int ct = 0; ct < 4; ++ct)
#pragma unroll
        for (int r = 0; r < 4; ++r)
            Ph[wv * 16 + rbase + r][ct * 16 + lr] = f2bf(p[ct][r] * (1.f / sum[r]));
    // wave-local LDS dependency only

    f32x4 o_[4];
#pragma unroll
    for (int ct = 0; ct < 4; ++ct) o_[ct] = zero4;
#pragma unroll
    for (int ks = 0; ks < 2; ++ks) {
        const int kb = ks * 32 + kq;
        bf16x8 ph = *reinterpret_cast<const bf16x8*>(&Ph[wv * 16 + lr][kb]);
#pragma unroll
        for (int ct = 0; ct < 4; ++ct) {
            bf16x8 vh = *reinterpret_cast<const bf16x8*>(&Vth[ct * 16 + lr][kb]);
            o_[ct] = __builtin_amdgcn_mfma_f32_16x16x32_bf16(ph, vh, o_[ct], 0, 0, 0);
        }
    }
    const int rt_z = bb >> 4;
#pragma unroll
    for (int ct = 0; ct < 4; ++ct)
#pragma unroll
        for (int r = 0; r < 4; ++r) {
            const int srow = wv * 16 + rbase + r;
            const int d    = ct * 16 + lr;
            const int k    = nn * 4096 + srow * 64 + d;
            const int lz   = (((k >> 3) & 3) << 4) + (bb & 15);
            const size_t zi = (((size_t)rt_z * 1536 + (k >> 5)) * 64 + lz) * 8 + (k & 7);
            Zh[zi] = f2bf(o_[ct][r]);
        }
}

// ---------------- Kernel 3: output projection v13 (16 waves/CU) ----------------
// part[kg][b][o] = sum_{k in 3072-chunk} Z[b][k] W[o][k]
// grid 1024 = 16 kg x 64 units, 4 blocks/CU (LDS 34.4KB), single round.
// 48 subs of BK=64, rotated start. Per sub per wave: 4 W loads (4 rows x
// 256B segments) + 2 Z gload_lds (1KB each). vmcnt(4) steady state.
__global__ __launch_bounds__(256, 4) void k_lin(const unsigned short* __restrict__ Zh,
                                                const float* __restrict__ Wl,
                                                float* __restrict__ part) {
    __shared__ __align__(16) unsigned short Zlds[2][8][64][8];    // 16 KB
    __shared__ __align__(16) unsigned short Wbuf[4][2][16][72];   // 18.4 KB (144B rows)
    const int t  = threadIdx.x;
    const int wv = t >> 6, ln = t & 63;
    const int lr  = ln & 15;
    const int rhi = ln >> 4;                   // 0..3
    const int rbase = rhi * 4;
    const int kg   = blockIdx.x & 15;          // 0..15
    const int unit = blockIdx.x >> 4;          // 0..63
    const int o0   = unit * 64;
    const int srot = (unit * 3 + kg) % 48;     // per-block k-phase rotation
    const f32x4 zero4 = {0.f, 0.f, 0.f, 0.f};

    const float* wbase = Wl + (size_t)(o0 + wv * 16) * 49152 + kg * 3072 + lr * 4;
    char* wrow = (char*)&Wbuf[wv][0][0][0];

    f32x4 acc[4];
#pragma unroll
    for (int rt = 0; rt < 4; ++rt) acc[rt] = zero4;

    float4 wregA[4], wregB[4];
#define ROT(n_) ((srot + (n_)) < 48 ? (srot + (n_)) : (srot + (n_)) - 48)
    // W load instr i: rows i*4 + rhi (4 rows), lane takes 16B at lr*16 of the
    // row's 256B sub-slice -> 4 contiguous 256B segments (full 64B lines).
#define WLOAD(REG, sub_)                                                            \
    {                                                                               \
        const int rs_ = ROT(sub_);                                                  \
        _Pragma("unroll")                                                           \
        for (int i = 0; i < 4; ++i)                                                 \
            REG[i] = *reinterpret_cast<const float4*>(                              \
                wbase + (size_t)(i * 4 + rhi) * 49152 + rs_ * 64);                  \
    }
#define WWRITE(buf_, REG)                                                           \
    {                                                                               \
        _Pragma("unroll")                                                           \
        for (int i = 0; i < 4; ++i) {                                               \
            unsigned u0 = (unsigned)f2bf(REG[i].x) | ((unsigned)f2bf(REG[i].y) << 16); \
            unsigned u1 = (unsigned)f2bf(REG[i].z) | ((unsigned)f2bf(REG[i].w) << 16); \
            uint2 pk; pk.x = u0; pk.y = u1;                                         \
            *reinterpret_cast<uint2*>(wrow + ((buf_) * 16 + i * 4 + rhi) * 144 + lr * 8) = pk; \
        }                                                                           \
    }
    // Z stage: wave wv stages its rt=wv rows, 2 x 1KB contiguous gload_lds
#define ZSTAGE(buf_, sub_)                                                          \
    {                                                                               \
        const int kf0 = kg * 96 + ROT(sub_) * 2;                                    \
        _Pragma("unroll")                                                           \
        for (int q = 0; q < 2; ++q) {                                               \
            const unsigned short* src = Zh +                                        \
                ((size_t)(wv * 1536 + kf0 + q) * 64 + ln) * 8;                      \
            __builtin_amdgcn_global_load_lds((gvoid_t*)src,                         \
                (svoid_t*)&Zlds[buf_][wv * 2 + q][0][0], 16, 0, 0);                 \
        }                                                                           \
    }
#define COMPUTE(buf_)                                                               \
    {                                                                               \
        _Pragma("unroll")                                                           \
        for (int kfo = 0; kfo < 2; ++kfo) {                                         \
            bf16x8 wf = *reinterpret_cast<const bf16x8*>(                           \
                wrow + ((buf_) * 16 + lr) * 144 + kfo * 64 + rhi * 16);             \
            _Pragma("unroll")                                                       \
            for (int rt = 0; rt < 4; ++rt) {                                        \
                bf16x8 z = *reinterpret_cast<const bf16x8*>(&Zlds[buf_][rt * 2 + kfo][ln][0]); \
                acc[rt] = __builtin_amdgcn_mfma_f32_16x16x32_bf16(z, wf, acc[rt], 0, 0, 0); \
            }                                                                       \
        }                                                                           \
    }

    // ---- prologue ----
    ZSTAGE(0, 0)
    WLOAD(wregA, 0)
    asm volatile("s_waitcnt vmcnt(0)" ::: "memory");
    WWRITE(0, wregA)
    WLOAD(wregB, 1)                      // W(1) in flight across sub 0
    __syncthreads();                     // Zlds[0] visible

    // ---- main loop: logical subs 0..45 ----
    for (int sp = 0; sp < 23; ++sp) {
        const int s0 = sp * 2;
        // sub s0 (even): compute buf0, WLOAD->A, WWRITE B
        ZSTAGE(1, s0 + 1)
        WLOAD(wregA, s0 + 2)
        COMPUTE(0)
        asm volatile("s_waitcnt vmcnt(4)" ::: "memory");   // W(s0+1)+Z(s0+1) done; W(s0+2) out
        WWRITE(1, wregB)
        __syncthreads();
        // sub s0+1 (odd): compute buf1, WLOAD->B, WWRITE A
        ZSTAGE(0, s0 + 2)
        WLOAD(wregB, s0 + 3)
        COMPUTE(1)
        asm volatile("s_waitcnt vmcnt(4)" ::: "memory");
        WWRITE(0, wregA)
        __syncthreads();
    }
    // ---- tail: logical subs 46 (even), 47 (odd); W(47) in flight in wregB ----
    ZSTAGE(1, 47)
    COMPUTE(0)
    asm volatile("s_waitcnt vmcnt(0)" ::: "memory");
    WWRITE(1, wregB)
    __syncthreads();
    COMPUTE(1)
#undef ROT
#undef WLOAD
#undef WWRITE
#undef ZSTAGE
#undef COMPUTE

    const int ocol = o0 + wv * 16 + lr;
#pragma unroll
    for (int rt = 0; rt < 4; ++rt)
#pragma unroll
        for (int r = 0; r < 4; ++r)
            part[((size_t)kg * 64 + rt * 16 + rbase + r) * 4096 + ocol] = acc[rt][r];
}

// ---------------- Kernel 4: reduce 16 split-K partials + bias ----------------
__global__ __launch_bounds__(256) void k_reduce(const float* __restrict__ part,
                                                const float* __restrict__ bias,
                                                float* __restrict__ y) {
    const int idx = blockIdx.x * 256 + threadIdx.x;
    const int o = idx & 4095;
    const int b = idx >> 12;
    float s = bias[o];
#pragma unroll
    for (int kg = 0; kg < 16; ++kg)
        s += part[((size_t)kg * 64 + b) * 4096 + o];
    y[idx] = s;
}

extern "C" void kernel_launch(void* const* d_in, const int* in_sizes, int n_in,
                              void* d_out, int out_size, void* d_ws, size_t ws_size,
                              hipStream_t stream) {
    const float* x  = (const float*)d_in[0];
    const float* Wp = (const float*)d_in[1];
    const float* Wl = (const float*)d_in[2];
    const float* bl = (const float*)d_in[3];
    float* out = (float*)d_out;

    unsigned short* qkvb = (unsigned short*)d_ws;                       // 9437184 u16
    unsigned short* Zh   = (unsigned short*)((char*)d_ws + 18874368);   // 3145728 u16
    float*          part = (float*)((char*)d_ws + 25165824);            // 16x64x4096 f32
    float* y    = out;
    float* msk  = out + 262144;

    hipLaunchKernelGGL(k_qkv,    dim3(576),  dim3(256), 0, stream, x, Wp, qkvb);
    hipLaunchKernelGGL(k_attn,   dim3(768),  dim3(256), 0, stream, qkvb, msk, Zh);
    hipLaunchKernelGGL(k_lin,    dim3(1024), dim3(256), 0, stream, Zh, Wl, part);
    hipLaunchKernelGGL(k_reduce, dim3(1024), dim3(256), 0, stream, part, bl, y);
}

// Round 19
// 225.089 us; speedup vs baseline: 1.2302x; 1.2302x over previous
//
#include <hip/hip_runtime.h>
#include <math.h>

// B=64, S=64, H_DIM=768, N_HEADS=12, D=64. All I/O f32.
// 4 kernels. ws bytes: qkvb u16[9437184] @0 ; Zh u16[3145728] @18874368 ;
//           part f32[8][64][4096] @25165824
// d_out f32: y [262144] then masked_scores [3145728].
// Masked positions: ref=-inf -> finite NEG_BIG (never materialize inf:
// finite-math folds ==-INFINITY; expf(NEG_BIG-m)==0).
// All GEMMs plain bf16 MFMA, f32 accum.
// mfma_f32_16x16x32_bf16: A row=ln&15,k=(ln>>4)*8+j; B col=ln&15;
// C/D col=ln&15,row=(ln>>4)*4+reg.
// Z frag order: z_flat[b][k] at ((rt*1536+kf)*64+lz)*8+j, rt=b>>4, kf=k>>5,
// lz=((k>>3)&3)*16+(b&15), j=k&7 -> contiguous 1KB wave reads/stages.
// k_lin v14b = r16's v12 (best: 271us) + NON-TEMPORAL W loads (r18 fixed:
// __builtin_nontemporal_load needs a clang vector type, not HIP float4 ->
// use f32x4 ext_vector_type). Theory: W is single-touch (805MB) and sweeps
// L2/L3 ~3x per launch, evicting the REUSED data (each kg's 768KB Z slice
// = 48MB of intended L2 hits per kg; part). nt W-loads skip L2/L3
// allocation, preserving residency for Z. Falsified so far: segment size
// (r15), channel aliasing (r16, +8us), waves/CU (r17).

#define NEG_BIG (-1.0e30f)

typedef __attribute__((ext_vector_type(8))) short bf16x8;
typedef __attribute__((ext_vector_type(4))) float f32x4;
typedef const __attribute__((address_space(1))) void gvoid_t;
typedef __attribute__((address_space(3))) void svoid_t;

static __device__ __forceinline__ unsigned short f2bf(float x) {
    unsigned u = __builtin_bit_cast(unsigned, x);
    return (unsigned short)((u + 0x7FFFu + ((u >> 16) & 1u)) >> 16);   // RNE
}
static __device__ __forceinline__ ushort4 f2bf4(float4 v) {
    ushort4 r; r.x = f2bf(v.x); r.y = f2bf(v.y); r.z = f2bf(v.z); r.w = f2bf(v.w); return r;
}

// ---------------- Kernel 1: QKV GEMM, plain bf16 MFMA ----------------
__global__ __launch_bounds__(256, 4) void k_qkv(const float* __restrict__ X,
                                                const float* __restrict__ Wp,
                                                unsigned short* __restrict__ qkvb) {
    __shared__ unsigned short Ah[128][72];
    __shared__ unsigned short Bh[128][72];
    const int t  = threadIdx.x;
    const int wv = t >> 6, ln = t & 63;
    const int lr = ln & 15;
    const int kq = (ln >> 4) * 8;
    const int rbase = (ln >> 4) * 4;
    const int m0 = (blockIdx.x / 18) * 128;
    const int j0 = (blockIdx.x % 18) * 128;
    const f32x4 zero4 = {0.f, 0.f, 0.f, 0.f};

    f32x4 acc[2][8];
#pragma unroll
    for (int rt = 0; rt < 2; ++rt)
#pragma unroll
        for (int ct = 0; ct < 8; ++ct) acc[rt][ct] = zero4;

    for (int k0 = 0; k0 < 768; k0 += 64) {
#pragma unroll
        for (int i = 0; i < 8; ++i) {
            const int q   = t + 256 * i;
            const int row = q >> 4;
            const int kc  = (q & 15) * 4;
            float4 xa = *reinterpret_cast<const float4*>(&X[(size_t)(m0 + row) * 768 + k0 + kc]);
            *reinterpret_cast<ushort4*>(&Ah[row][kc]) = f2bf4(xa);
            float4 wb = *reinterpret_cast<const float4*>(&Wp[(size_t)(j0 + row) * 768 + k0 + kc]);
            *reinterpret_cast<ushort4*>(&Bh[row][kc]) = f2bf4(wb);
        }
        __syncthreads();
#pragma unroll
        for (int ks = 0; ks < 2; ++ks) {
            const int kb = ks * 32 + kq;
            bf16x8 a0 = *reinterpret_cast<const bf16x8*>(&Ah[wv * 32 + lr][kb]);
            bf16x8 a1 = *reinterpret_cast<const bf16x8*>(&Ah[wv * 32 + 16 + lr][kb]);
#pragma unroll
            for (int ct = 0; ct < 8; ++ct) {
                bf16x8 bh = *reinterpret_cast<const bf16x8*>(&Bh[ct * 16 + lr][kb]);
                acc[0][ct] = __builtin_amdgcn_mfma_f32_16x16x32_bf16(a0, bh, acc[0][ct], 0, 0, 0);
                acc[1][ct] = __builtin_amdgcn_mfma_f32_16x16x32_bf16(a1, bh, acc[1][ct], 0, 0, 0);
            }
        }
        __syncthreads();
    }
#pragma unroll
    for (int rt = 0; rt < 2; ++rt)
#pragma unroll
        for (int ct = 0; ct < 8; ++ct)
#pragma unroll
            for (int r = 0; r < 4; ++r) {
                const int m = m0 + wv * 32 + rt * 16 + rbase + r;
                const int j = j0 + ct * 16 + lr;
                const int b = m >> 6, s = m & 63;
                const int n = j / 192, f = j % 192;
                qkvb[(((size_t)b * 12 + n) * 64 + s) * 192 + f] = f2bf(acc[rt][ct][r]);
            }
}

// ---------------- Kernel 2: attention per (b,n), plain bf16 MFMA ----------------
__global__ __launch_bounds__(256, 4) void k_attn(const unsigned short* __restrict__ qkvb,
                                                 float* __restrict__ msk,
                                                 unsigned short* __restrict__ Zh) {
    __shared__ unsigned short Qh[64][72];
    __shared__ unsigned short Kh[64][72];
    __shared__ unsigned short Vth[64][72];   // V transposed [d][s]
    __shared__ unsigned short Ph[64][72];
    const int t  = threadIdx.x;
    const int wv = t >> 6, ln = t & 63;
    const int lr = ln & 15;
    const int kq = (ln >> 4) * 8;
    const int rbase = (ln >> 4) * 4;
    const int bn = blockIdx.x;
    const int bb = bn / 12, nn = bn % 12;
    const unsigned short* base = qkvb + (size_t)bn * 12288;
    const f32x4 zero4 = {0.f, 0.f, 0.f, 0.f};

#pragma unroll
    for (int i = 0; i < 6; ++i) {
        const int q   = t + 256 * i;
        const int row = q / 24;
        const int c8  = (q % 24) * 8;
        const int sec = c8 >> 6;
        const int d0  = c8 & 63;
        bf16x8 v = *reinterpret_cast<const bf16x8*>(&base[(size_t)row * 192 + c8]);
        if (sec == 0) {
            *reinterpret_cast<bf16x8*>(&Qh[row][d0]) = v;
        } else if (sec == 1) {
            *reinterpret_cast<bf16x8*>(&Kh[row][d0]) = v;
        } else {
#pragma unroll
            for (int jj = 0; jj < 8; ++jj) Vth[d0 + jj][row] = (unsigned short)v[jj];
        }
    }
    __syncthreads();

    f32x4 acc[4];
#pragma unroll
    for (int ct = 0; ct < 4; ++ct) acc[ct] = zero4;
#pragma unroll
    for (int ks = 0; ks < 2; ++ks) {
        const int kb = ks * 32 + kq;
        bf16x8 qh = *reinterpret_cast<const bf16x8*>(&Qh[wv * 16 + lr][kb]);
#pragma unroll
        for (int ct = 0; ct < 4; ++ct) {
            bf16x8 kh = *reinterpret_cast<const bf16x8*>(&Kh[ct * 16 + lr][kb]);
            acc[ct] = __builtin_amdgcn_mfma_f32_16x16x32_bf16(qh, kh, acc[ct], 0, 0, 0);
        }
    }

    float s_[4][4];
#pragma unroll
    for (int ct = 0; ct < 4; ++ct)
#pragma unroll
        for (int r = 0; r < 4; ++r) {
            const int row = wv * 16 + rbase + r;
            const int col = ct * 16 + lr;
            float s = (col > row) ? NEG_BIG : acc[ct][r] * 0.125f;
            s_[ct][r] = s;
            msk[(size_t)bn * 4096 + (size_t)row * 64 + col] = s;
        }
    float m[4], sum[4], p[4][4];
#pragma unroll
    for (int r = 0; r < 4; ++r)
        m[r] = fmaxf(fmaxf(s_[0][r], s_[1][r]), fmaxf(s_[2][r], s_[3][r]));
#pragma unroll
    for (int off = 1; off <= 8; off <<= 1)
#pragma unroll
        for (int r = 0; r < 4; ++r) m[r] = fmaxf(m[r], __shfl_xor(m[r], off));
#pragma unroll
    for (int r = 0; r < 4; ++r) sum[r] = 0.f;
#pragma unroll
    for (int ct = 0; ct < 4; ++ct)
#pragma unroll
        for (int r = 0; r < 4; ++r) { p[ct][r] = expf(s_[ct][r] - m[r]); sum[r] += p[ct][r]; }
#pragma unroll
    for (int off = 1; off <= 8; off <<= 1)
#pragma unroll
        for (int r = 0; r < 4; ++r) sum[r] += __shfl_xor(sum[r], off);
#pragma unroll
    for (int ct = 0; ct < 4; ++ct)
#pragma unroll
        for (int r = 0; r < 4; ++r)
            Ph[wv * 16 + rbase + r][ct * 16 + lr] = f2bf(p[ct][r] * (1.f / sum[r]));
    // wave-local LDS dependency only

    f32x4 o_[4];
#pragma unroll
    for (int ct = 0; ct < 4; ++ct) o_[ct] = zero4;
#pragma unroll
    for (int ks = 0; ks < 2; ++ks) {
        const int kb = ks * 32 + kq;
        bf16x8 ph = *reinterpret_cast<const bf16x8*>(&Ph[wv * 16 + lr][kb]);
#pragma unroll
        for (int ct = 0; ct < 4; ++ct) {
            bf16x8 vh = *reinterpret_cast<const bf16x8*>(&Vth[ct * 16 + lr][kb]);
            o_[ct] = __builtin_amdgcn_mfma_f32_16x16x32_bf16(ph, vh, o_[ct], 0, 0, 0);
        }
    }
    const int rt_z = bb >> 4;
#pragma unroll
    for (int ct = 0; ct < 4; ++ct)
#pragma unroll
        for (int r = 0; r < 4; ++r) {
            const int srow = wv * 16 + rbase + r;
            const int d    = ct * 16 + lr;
            const int k    = nn * 4096 + srow * 64 + d;
            const int lz   = (((k >> 3) & 3) << 4) + (bb & 15);
            const size_t zi = (((size_t)rt_z * 1536 + (k >> 5)) * 64 + lz) * 8 + (k & 7);
            Zh[zi] = f2bf(o_[ct][r]);
        }
}

// ---------------- Kernel 3: output projection v14b (r16 + nt W loads) ----------------
// part[kg][b][o] = sum_{k in 6144-chunk} Z[b][k] W[o][k]
// grid 512 = 8 kgroups x 64 units. 48 subs of BK=128, rotated start
// srot=(unit*3+kg)%48. W loads NON-TEMPORAL (no L2/L3 allocation).
__global__ __launch_bounds__(256, 2) void k_lin(const unsigned short* __restrict__ Zh,
                                                const float* __restrict__ Wl,
                                                float* __restrict__ part) {
    __shared__ __align__(16) unsigned short Zlds[2][16][64][8];   // 32 KB
    __shared__ __align__(16) unsigned short Wbuf[4][2][16][136];  // 34.8 KB
    const int t  = threadIdx.x;
    const int wv = t >> 6, ln = t & 63;
    const int lr = ln & 15;
    const int rbase = (ln >> 4) * 4;
    const int kg   = blockIdx.x & 7;
    const int unit = blockIdx.x >> 3;
    const int o0   = unit * 64;
    const int srot = (unit * 3 + kg) % 48;     // per-block k-phase rotation
    const f32x4 zero4 = {0.f, 0.f, 0.f, 0.f};

    const int rlo = (ln >= 32) ? 1 : 0;
    const float* wbase = Wl + (size_t)(o0 + wv * 16) * 49152 + kg * 6144 + (ln & 31) * 4;
    char* wrow = (char*)&Wbuf[wv][0][0][0];

    f32x4 acc[4];
#pragma unroll
    for (int rt = 0; rt < 4; ++rt) acc[rt] = zero4;

    f32x4 wregA[8], wregB[8];   // clang vector type: valid for nontemporal builtin
    // logical sub n -> rotated physical sub
#define ROT(n_) ((srot + (n_)) < 48 ? (srot + (n_)) : (srot + (n_)) - 48)
    // NON-TEMPORAL: W is single-touch; don't allocate in L2/L3 (keep Z hot).
#define WLOAD(REG, sub_)                                                            \
    {                                                                               \
        const int rs_ = ROT(sub_);                                                  \
        _Pragma("unroll")                                                           \
        for (int i = 0; i < 8; ++i)                                                 \
            REG[i] = __builtin_nontemporal_load(reinterpret_cast<const f32x4*>(     \
                wbase + (size_t)(2 * i + rlo) * 49152 + rs_ * 128));                \
    }
#define WWRITE(buf_, REG)                                                           \
    {                                                                               \
        _Pragma("unroll")                                                           \
        for (int i = 0; i < 8; ++i) {                                               \
            unsigned u0 = (unsigned)f2bf(REG[i].x) | ((unsigned)f2bf(REG[i].y) << 16); \
            unsigned u1 = (unsigned)f2bf(REG[i].z) | ((unsigned)f2bf(REG[i].w) << 16); \
            uint2 pk; pk.x = u0; pk.y = u1;                                         \
            *reinterpret_cast<uint2*>(wrow + ((buf_) * 16 + 2 * i + rlo) * 272 + (ln & 31) * 8) = pk; \
        }                                                                           \
    }
#define ZSTAGE(buf_, sub_)                                                          \
    {                                                                               \
        const int kf0 = kg * 192 + ROT(sub_) * 4;                                   \
        _Pragma("unroll")                                                           \
        for (int q = 0; q < 4; ++q) {                                               \
            const unsigned short* src = Zh +                                        \
                ((size_t)(wv * 1536 + kf0 + q) * 64 + ln) * 8;                      \
            __builtin_amdgcn_global_load_lds((gvoid_t*)src,                         \
                (svoid_t*)&Zlds[buf_][wv * 4 + q][0][0], 16, 0, 0);                 \
        }                                                                           \
    }
#define COMPUTE(buf_)                                                               \
    {                                                                               \
        _Pragma("unroll")                                                           \
        for (int kfo = 0; kfo < 4; ++kfo) {                                         \
            bf16x8 wf = *reinterpret_cast<const bf16x8*>(                           \
                wrow + ((buf_) * 16 + lr) * 272 + kfo * 64 + (ln >> 4) * 16);       \
            _Pragma("unroll")                                                       \
            for (int rt = 0; rt < 4; ++rt) {                                        \
                bf16x8 z = *reinterpret_cast<const bf16x8*>(&Zlds[buf_][rt * 4 + kfo][ln][0]); \
                acc[rt] = __builtin_amdgcn_mfma_f32_16x16x32_bf16(z, wf, acc[rt], 0, 0, 0); \
            }                                                                       \
        }                                                                           \
    }

    // ---- prologue ----
    ZSTAGE(0, 0)
    WLOAD(wregA, 0)
    asm volatile("s_waitcnt vmcnt(0)" ::: "memory");
    WWRITE(0, wregA)
    WLOAD(wregB, 1)                      // W(1) in flight across sub 0
    __syncthreads();                     // Zlds[0] visible

    // ---- main loop: logical subs 0..45 ----
    for (int sp = 0; sp < 23; ++sp) {
        const int s0 = sp * 2;
        // sub s0 (even): compute buf0, WLOAD->A, WWRITE B
        ZSTAGE(1, s0 + 1)
        WLOAD(wregA, s0 + 2)
        COMPUTE(0)
        asm volatile("s_waitcnt vmcnt(8)" ::: "memory");   // W(s0+1)+Z(s0+1) done; W(s0+2) out
        WWRITE(1, wregB)
        __syncthreads();
        // sub s0+1 (odd): compute buf1, WLOAD->B, WWRITE A
        ZSTAGE(0, s0 + 2)
        WLOAD(wregB, s0 + 3)
        COMPUTE(1)
        asm volatile("s_waitcnt vmcnt(8)" ::: "memory");
        WWRITE(0, wregA)
        __syncthreads();
    }
    // ---- tail: logical subs 46 (even), 47 (odd); W(47) in flight in wregB ----
    ZSTAGE(1, 47)
    COMPUTE(0)
    asm volatile("s_waitcnt vmcnt(0)" ::: "memory");
    WWRITE(1, wregB)
    __syncthreads();
    COMPUTE(1)
#undef ROT
#undef WLOAD
#undef WWRITE
#undef ZSTAGE
#undef COMPUTE

    const int ocol = o0 + wv * 16 + lr;
#pragma unroll
    for (int rt = 0; rt < 4; ++rt)
#pragma unroll
        for (int r = 0; r < 4; ++r)
            part[((size_t)kg * 64 + rt * 16 + rbase + r) * 4096 + ocol] = acc[rt][r];
}

// ---------------- Kernel 4: reduce 8 split-K partials + bias ----------------
__global__ __launch_bounds__(256) void k_reduce(const float* __restrict__ part,
                                                const float* __restrict__ bias,
                                                float* __restrict__ y) {
    const int idx = blockIdx.x * 256 + threadIdx.x;
    const int o = idx & 4095;
    const int b = idx >> 12;
    float s = bias[o];
#pragma unroll
    for (int kg = 0; kg < 8; ++kg)
        s += part[((size_t)kg * 64 + b) * 4096 + o];
    y[idx] = s;
}

extern "C" void kernel_launch(void* const* d_in, const int* in_sizes, int n_in,
                              void* d_out, int out_size, void* d_ws, size_t ws_size,
                              hipStream_t stream) {
    const float* x  = (const float*)d_in[0];
    const float* Wp = (const float*)d_in[1];
    const float* Wl = (const float*)d_in[2];
    const float* bl = (const float*)d_in[3];
    float* out = (float*)d_out;

    unsigned short* qkvb = (unsigned short*)d_ws;                       // 9437184 u16
    unsigned short* Zh   = (unsigned short*)((char*)d_ws + 18874368);   // 3145728 u16
    float*          part = (float*)((char*)d_ws + 25165824);            // 8x64x4096 f32
    float* y    = out;
    float* msk  = out + 262144;

    hipLaunchKernelGGL(k_qkv,    dim3(576),  dim3(256), 0, stream, x, Wp, qkvb);
    hipLaunchKernelGGL(k_attn,   dim3(768),  dim3(256), 0, stream, qkvb, msk, Zh);
    hipLaunchKernelGGL(k_lin,    dim3(512),  dim3(256), 0, stream, Zh, Wl, part);
    hipLaunchKernelGGL(k_reduce, dim3(1024), dim3(256), 0, stream, part, bl, y);
}